// Round 7
// baseline (392.914 us; speedup 1.0000x reference)
//
#include <hip/hip_runtime.h>
#include <hip/hip_bf16.h>

#define N_NODES   100000
#define N_EDGES   1600000
#define N_GRAPHS  1024
#define EMB       32
#define HID       64
#define N_CLASSES 10
#define SCAN_BLOCKS 391   // ceil(100000/256)
#define NCOMBO 153        // 17 shape ids x 9 color ids
#define BUCK_NODES 448    // nodes per dst-bucket
#define NBUCK 224         // ceil(100000/448)
#define BIN_CAP 8192      // per-bucket staging capacity (mean 7168, sigma ~85)
#define EPB 8192          // edges per binA block

// ---------------- prep: combo[v], per-graph counts (no deg dependency) ----------------
__global__ __launch_bounds__(256) void prep_kernel(
    const int* __restrict__ sid, const int* __restrict__ cid,
    const int* __restrict__ batch, int* __restrict__ combo, int* __restrict__ cnt) {
    int v = blockIdx.x * 256 + threadIdx.x;
    if (v < N_NODES) {
        combo[v] = sid[v] * 9 + cid[v];
        atomicAdd(&cnt[batch[v]], 1);
    }
}

// ---------------- combined table: TC[s*9+c][j] = (st[s]@W1)[j] + (ct[c]@W1)[j] ----------------
__global__ __launch_bounds__(64) void tc_kernel(
    const float* __restrict__ st, const float* __restrict__ ct,
    const float* __restrict__ W1, float* __restrict__ TC) {
    int r = blockIdx.x, j = threadIdx.x;
    int s = r / 9, c = r % 9;
    float acc = 0.0f;
    if (s != 0) {
#pragma unroll
        for (int k = 0; k < EMB; ++k) acc = fmaf(st[s * EMB + k], W1[k * HID + j], acc);
    }
    if (c != 0) {
#pragma unroll
        for (int k = 0; k < EMB; ++k) acc = fmaf(ct[c * EMB + k], W1[k * HID + j], acc);
    }
    TC[r * HID + j] = acc;
}

// ---------------- binA: block-local counting sort by dst-bucket, chunked flush ----------------
__global__ __launch_bounds__(512) void binA_kernel(
    const int* __restrict__ src, const int* __restrict__ dst,
    const int* __restrict__ combo, int* __restrict__ gcur,
    int2* __restrict__ gbin) {
    __shared__ int2 stg[EPB];            // 64 KB
    __shared__ int hist[NBUCK];
    __shared__ int base[NBUCK + 1];
    __shared__ int gstart[NBUCK];
    __shared__ int scanbuf[256];
    int t = threadIdx.x;
    int e0 = blockIdx.x * EPB;
    for (int i = t; i < NBUCK; i += 512) hist[i] = 0;
    __syncthreads();

    int2 myq[16];
    int mybo[16];
#pragma unroll
    for (int i = 0; i < 16; ++i) {
        int e = e0 + t + i * 512;
        if (e < N_EDGES) {
            int d = dst[e];
            int s = src[e];
            unsigned b = (unsigned)d / BUCK_NODES;
            int off = atomicAdd(&hist[b], 1);
            myq[i].x = s | (combo[s] << 17);
            myq[i].y = d;
            mybo[i] = (int)(b << 16) | off;
        } else {
            mybo[i] = -1;
        }
    }
    __syncthreads();

    int h = (t < NBUCK) ? hist[t] : 0;
    if (t < 256) scanbuf[t] = h;
    __syncthreads();
#pragma unroll
    for (int off = 1; off < 256; off <<= 1) {
        int x = (t < 256 && t >= off) ? scanbuf[t - off] : 0;
        __syncthreads();
        if (t < 256) scanbuf[t] += x;
        __syncthreads();
    }
    if (t < NBUCK) base[t] = scanbuf[t] - h;
    if (t == 0) base[NBUCK] = scanbuf[255];
    __syncthreads();
#pragma unroll
    for (int i = 0; i < 16; ++i) {
        if (mybo[i] >= 0) {
            int b = mybo[i] >> 16, off = mybo[i] & 0xFFFF;
            stg[base[b] + off] = myq[i];
        }
    }
    if (t < NBUCK) {
        int n = hist[t];
        gstart[t] = n ? atomicAdd(&gcur[t], n) : 0;
    }
    __syncthreads();
    int total = base[NBUCK];
    for (int i = t; i < total; i += 512) {
        int2 q = stg[i];
        unsigned b = (unsigned)q.y / BUCK_NODES;
        gbin[(size_t)b * BIN_CAP + gstart[b] + (i - base[b])] = q;
    }
}

// ---------------- degB: per-bucket degree count from binned edges; dis = rsqrt(1+deg) ----------------
// Replaces the 66us global-atomic deg_kernel: counts live in LDS, writes are
// contiguous per-bucket (single-XCD window, ~2KB) -> no cross-XCD thrash.
__global__ __launch_bounds__(256) void degB_kernel(
    const int2* __restrict__ gbin, const int* __restrict__ gcur,
    int* __restrict__ degi, float* __restrict__ dis) {
    __shared__ int curs[BUCK_NODES];
    int b = blockIdx.x, t = threadIdx.x;
    for (int i = t; i < BUCK_NODES; i += 256) curs[i] = 0;
    __syncthreads();
    int n = gcur[b];
    const int2* mybin = gbin + (size_t)b * BIN_CAP;
    for (int i = t; i < n; i += 256) {
        int2 q = mybin[i];
        atomicAdd(&curs[q.y - b * BUCK_NODES], 1);
    }
    __syncthreads();
    for (int i = t; i < BUCK_NODES; i += 256) {
        int v = b * BUCK_NODES + i;
        if (v < N_NODES) {
            int d = curs[i];
            degi[v] = d;
            dis[v] = rsqrtf(1.0f + (float)d);
        }
    }
}

// ---------------- 3-pass exclusive scan of degrees -> rowptr ----------------
__global__ __launch_bounds__(256) void scanA_kernel(const int* __restrict__ degi,
                                                    int* __restrict__ rowptr,
                                                    int* __restrict__ bsum) {
    __shared__ int s[256];
    int t = threadIdx.x, b = blockIdx.x;
    int v = b * 256 + t;
    int d = (v < N_NODES) ? degi[v] : 0;
    s[t] = d; __syncthreads();
#pragma unroll
    for (int off = 1; off < 256; off <<= 1) {
        int x = (t >= off) ? s[t - off] : 0;
        __syncthreads();
        s[t] += x;
        __syncthreads();
    }
    if (v < N_NODES) rowptr[v] = s[t] - d;
    if (t == 255) bsum[b] = s[255];
}

__global__ __launch_bounds__(512) void scanB_kernel(int* __restrict__ bsum) {
    __shared__ int s[512];
    int t = threadIdx.x;
    int d = (t < SCAN_BLOCKS) ? bsum[t] : 0;
    s[t] = d; __syncthreads();
#pragma unroll
    for (int off = 1; off < 512; off <<= 1) {
        int x = (t >= off) ? s[t - off] : 0;
        __syncthreads();
        s[t] += x;
        __syncthreads();
    }
    if (t < SCAN_BLOCKS) bsum[t] = s[t] - d;
}

__global__ __launch_bounds__(256) void scanC_kernel(int* __restrict__ rowptr,
                                                    const int* __restrict__ bsum) {
    int t = threadIdx.x, b = blockIdx.x;
    int v = b * 256 + t;
    if (v < N_NODES) rowptr[v] += bsum[b];
    if (b == 0 && t == 0) rowptr[N_NODES] = N_EDGES;
}

// ---------------- binB: per-bucket fine scatter to CSR (one block per bucket) ----------------
__global__ __launch_bounds__(256) void binB_kernel(
    const int2* __restrict__ gbin, const int* __restrict__ gcur,
    const int* __restrict__ rowptr, const float* __restrict__ dis,
    int2* __restrict__ epack) {
    __shared__ int curs[BUCK_NODES];
    int b = blockIdx.x, t = threadIdx.x;
    for (int i = t; i < BUCK_NODES; i += 256) curs[i] = 0;
    __syncthreads();
    int n = gcur[b];
    const int2* mybin = gbin + (size_t)b * BIN_CAP;
    for (int i = t; i < n; i += 256) {
        int2 q = mybin[i];
        int local = q.y - b * BUCK_NODES;
        int r = atomicAdd(&curs[local], 1);
        int2 rec;
        rec.x = q.x;
        rec.y = __float_as_int(dis[q.x & 0x1FFFF]);
        epack[rowptr[q.y] + r] = rec;
    }
}

// ---------------- layer-1 aggregate from combined table -> x1 ----------------
__global__ __launch_bounds__(256) void agg1_kernel(
    const int2* __restrict__ epack, const int* __restrict__ rowptr,
    const int* __restrict__ combo, const float* __restrict__ dis,
    const float* __restrict__ TC, const float* __restrict__ b1,
    float* __restrict__ x1) {
    __shared__ __align__(16) float TCs[NCOMBO * HID];   // 39,168 B
    int t = threadIdx.x;
    {
        const float4* s4 = (const float4*)TC;
        float4* d4 = (float4*)TCs;
        for (int i = t; i < NCOMBO * HID / 4; i += 256) d4[i] = s4[i];
    }
    __syncthreads();
    int lane = t & 63, w = t >> 6;
    float bias = b1[lane];
    int v0 = (blockIdx.x * 4 + w) * 4;
    for (int n = 0; n < 4; ++n) {
        int v = v0 + n;
        int e  = __builtin_amdgcn_readfirstlane(rowptr[v]);
        int e1 = __builtin_amdgcn_readfirstlane(rowptr[v + 1]);
        float acc = 0.0f;
        for (; e + 8 <= e1; e += 8) {
            int2 q[8];
#pragma unroll
            for (int i = 0; i < 8; ++i) q[i] = epack[e + i];
#pragma unroll
            for (int i = 0; i < 8; ++i)
                acc = fmaf(__int_as_float(q[i].y),
                           TCs[((unsigned)q[i].x >> 17) * HID + lane], acc);
        }
        for (; e < e1; ++e) {
            int2 q = epack[e];
            acc = fmaf(__int_as_float(q.y),
                       TCs[((unsigned)q.x >> 17) * HID + lane], acc);
        }
        float dv = dis[v];
        float hv = TCs[combo[v] * HID + lane];
        float val = dv * fmaf(hv, dv, acc) + bias;
        x1[(size_t)v * HID + lane] = val > 0.0f ? val : 0.0f;
    }
}

// ---------------- mm2 in place: x[v] = x[v] @ W2; W2 column in 64 VGPRs ----------------
// (256,2): 8 waves/CU for latency hiding; wcol[64] fits the 256-VGPR budget.
__global__ __launch_bounds__(256, 2) void mm2_kernel(float* __restrict__ x,
                                                     const float* __restrict__ W2) {
    __shared__ __align__(16) float xs[4][HID];
    int t = threadIdx.x, lane = t & 63, w = t >> 6;
    float wcol[HID];
#pragma unroll
    for (int k = 0; k < HID; ++k) wcol[k] = W2[k * HID + lane];
    int v0 = (blockIdx.x * 4 + w) * 16;
    for (int n = 0; n < 16; ++n) {
        int v = v0 + n;
        if (v >= N_NODES) return;
        xs[w][lane] = x[(size_t)v * HID + lane];
        float acc = 0.0f;
#pragma unroll
        for (int k4 = 0; k4 < HID / 4; ++k4) {
            float4 xv = *(const float4*)(&xs[w][k4 * 4]);
            acc = fmaf(xv.x, wcol[k4 * 4 + 0], acc);
            acc = fmaf(xv.y, wcol[k4 * 4 + 1], acc);
            acc = fmaf(xv.z, wcol[k4 * 4 + 2], acc);
            acc = fmaf(xv.w, wcol[k4 * 4 + 3], acc);
        }
        x[(size_t)v * HID + lane] = acc;
    }
}

// ---------------- layer-2 aggregate + fused mean-pool accumulation ----------------
// float4 gather: lane = (sub-edge:2 | channel-quad:4); 4 edges per wave-instruction.
__global__ __launch_bounds__(256) void agg2_pool_kernel(
    const int2* __restrict__ epack, const int* __restrict__ rowptr,
    const float* __restrict__ h2, const float* __restrict__ dis,
    const float* __restrict__ b2, const int* __restrict__ batch,
    float* __restrict__ pooled) {
    int t = threadIdx.x, lane = t & 63;
    int v = blockIdx.x * 4 + (t >> 6);
    int sub = lane >> 4;             // 0..3: edge slot within group
    int cq  = (lane & 15) << 2;      // channel quad base 0,4,...,60
    int e  = __builtin_amdgcn_readfirstlane(rowptr[v]);
    int e1 = __builtin_amdgcn_readfirstlane(rowptr[v + 1]);
    float4 acc = make_float4(0.f, 0.f, 0.f, 0.f);
    for (; e + 8 <= e1; e += 8) {
        int2 qa = epack[e + sub];
        int2 qb = epack[e + 4 + sub];
        float4 ga = *(const float4*)&h2[(size_t)(qa.x & 0x1FFFF) * HID + cq];
        float4 gb = *(const float4*)&h2[(size_t)(qb.x & 0x1FFFF) * HID + cq];
        float wa = __int_as_float(qa.y), wb = __int_as_float(qb.y);
        acc.x = fmaf(wa, ga.x, acc.x); acc.y = fmaf(wa, ga.y, acc.y);
        acc.z = fmaf(wa, ga.z, acc.z); acc.w = fmaf(wa, ga.w, acc.w);
        acc.x = fmaf(wb, gb.x, acc.x); acc.y = fmaf(wb, gb.y, acc.y);
        acc.z = fmaf(wb, gb.z, acc.z); acc.w = fmaf(wb, gb.w, acc.w);
    }
    for (; e < e1; e += 4) {
        int i = e + sub;
        if (i < e1) {
            int2 q = epack[i];
            float4 g = *(const float4*)&h2[(size_t)(q.x & 0x1FFFF) * HID + cq];
            float wq = __int_as_float(q.y);
            acc.x = fmaf(wq, g.x, acc.x); acc.y = fmaf(wq, g.y, acc.y);
            acc.z = fmaf(wq, g.z, acc.z); acc.w = fmaf(wq, g.w, acc.w);
        }
    }
    // reduce across the 4 sub-edge groups (lanes xor 16, 32)
#pragma unroll
    for (int m = 16; m <= 32; m <<= 1) {
        acc.x += __shfl_xor(acc.x, m, 64);
        acc.y += __shfl_xor(acc.y, m, 64);
        acc.z += __shfl_xor(acc.z, m, 64);
        acc.w += __shfl_xor(acc.w, m, 64);
    }
    float dv = dis[v];
    float4 self4 = *(const float4*)&h2[(size_t)v * HID + cq];
    float4 bq = *(const float4*)&b2[cq];
    float4 val;
    val.x = dv * fmaf(self4.x, dv, acc.x) + bq.x;
    val.y = dv * fmaf(self4.y, dv, acc.y) + bq.y;
    val.z = dv * fmaf(self4.z, dv, acc.z) + bq.z;
    val.w = dv * fmaf(self4.w, dv, acc.w) + bq.w;
    val.x = val.x > 0.f ? val.x : 0.f;
    val.y = val.y > 0.f ? val.y : 0.f;
    val.z = val.z > 0.f ? val.z : 0.f;
    val.w = val.w > 0.f ? val.w : 0.f;
    if (lane < 16) {
        float* p = &pooled[batch[v] * HID + cq];
        unsafeAtomicAdd(p + 0, val.x);
        unsafeAtomicAdd(p + 1, val.y);
        unsafeAtomicAdd(p + 2, val.z);
        unsafeAtomicAdd(p + 3, val.w);
    }
}

// ---------------- logits ----------------
__global__ __launch_bounds__(64) void logits_kernel(
    const float* __restrict__ pooled, const int* __restrict__ cnt,
    const float* __restrict__ Wl, const float* __restrict__ bl,
    float* __restrict__ out) {
    __shared__ float row[HID];
    int g = blockIdx.x, t = threadIdx.x;
    int c = cnt[g]; if (c < 1) c = 1;
    row[t] = pooled[g * HID + t] / (float)c;
    __syncthreads();
    if (t < N_CLASSES) {
        float acc = bl[t];
#pragma unroll
        for (int k = 0; k < HID; ++k) acc = fmaf(row[k], Wl[k * N_CLASSES + t], acc);
        out[g * N_CLASSES + t] = acc;
    }
}

extern "C" void kernel_launch(void* const* d_in, const int* in_sizes, int n_in,
                              void* d_out, int out_size, void* d_ws, size_t ws_size,
                              hipStream_t stream) {
    const int*   shape_id = (const int*)d_in[0];
    const int*   color_id = (const int*)d_in[1];
    const int*   edge_idx = (const int*)d_in[2];
    const int*   batch    = (const int*)d_in[3];
    const float* st       = (const float*)d_in[4];
    const float* ct       = (const float*)d_in[5];
    const float* W1       = (const float*)d_in[6];
    const float* b1       = (const float*)d_in[7];
    const float* W2       = (const float*)d_in[8];
    const float* b2       = (const float*)d_in[9];
    const float* Wl       = (const float*)d_in[10];
    const float* bl       = (const float*)d_in[11];
    float* out = (float*)d_out;

    const int* src = edge_idx;
    const int* dst = edge_idx + N_EDGES;

    // workspace layout (aligned). gbin aliases x1h2 (dead until agg1).
    char* ws = (char*)d_ws;
    int*   combo  = (int*)  (ws + 0);            //   400,384 B
    float* dis    = (float*)(ws + 400384);       //   400,384 B
    int*   degi   = (int*)  (ws + 800768);       //   400,384 B
    int*   rowptr = (int*)  (ws + 1201152);      //   400,384 B
    int*   bsum   = (int*)  (ws + 1601536);      //     2,048 B
    float* TC     = (float*)(ws + 1603584);      //    39,424 B
    float* pooled = (float*)(ws + 1643008);      //   262,144 B
    int*   cnt    = (int*)  (ws + 1905152);      //     4,096 B
    int*   gcur   = (int*)  (ws + 1909248);      //     1,024 B
    int2*  epack  = (int2*) (ws + 1910272);      // 12,800,000 B
    float* x1h2   = (float*)(ws + 14710272);     // 25,600,000 B  (total ~40.3 MB)
    int2*  gbin   = (int2*) x1h2;                // alias: 224*8192*8 = 14.68 MB

    hipMemsetAsync(pooled, 0, N_GRAPHS * HID * sizeof(float) + N_GRAPHS * sizeof(int), stream);
    hipMemsetAsync(gcur, 0, NBUCK * sizeof(int), stream);

    // 1. per-node combo + per-graph counts
    prep_kernel<<<SCAN_BLOCKS, 256, 0, stream>>>(shape_id, color_id, batch, combo, cnt);

    // 2. combined (shape,color)->h1 table
    tc_kernel<<<NCOMBO, 64, 0, stream>>>(st, ct, W1, TC);

    // 3. bin edges by dst-bucket (chunked, coalesced writes)
    binA_kernel<<<(N_EDGES + EPB - 1) / EPB, 512, 0, stream>>>(src, dst, combo, gcur, gbin);

    // 4. per-bucket degree count + dis (replaces global-atomic deg_kernel)
    degB_kernel<<<NBUCK, 256, 0, stream>>>(gbin, gcur, degi, dis);

    // 5. exclusive scan -> rowptr
    scanA_kernel<<<SCAN_BLOCKS, 256, 0, stream>>>(degi, rowptr, bsum);
    scanB_kernel<<<1, 512, 0, stream>>>(bsum);
    scanC_kernel<<<SCAN_BLOCKS, 256, 0, stream>>>(rowptr, bsum);

    // 6. per-bucket scatter to CSR (single-XCD windows)
    binB_kernel<<<NBUCK, 256, 0, stream>>>(gbin, gcur, rowptr, dis, epack);

    // 7. layer-1 aggregate -> x1
    agg1_kernel<<<6250, 256, 0, stream>>>(epack, rowptr, combo, dis, TC, b1, x1h2);

    // 8. x1 @ W2 in place -> h2
    mm2_kernel<<<1563, 256, 0, stream>>>(x1h2, W2);

    // 9. layer-2 aggregate + pool (float4 gather, 4 edges/instr)
    agg2_pool_kernel<<<N_NODES / 4, 256, 0, stream>>>(epack, rowptr, x1h2, dis, b2,
                                                      batch, pooled);

    // 10. logits
    logits_kernel<<<N_GRAPHS, 64, 0, stream>>>(pooled, cnt, Wl, bl, out);
}

// Round 8
// 321.974 us; speedup vs baseline: 1.2203x; 1.2203x over previous
//
#include <hip/hip_runtime.h>
#include <hip/hip_bf16.h>
#include <hip/hip_fp16.h>

#define N_NODES   100000
#define N_EDGES   1600000
#define N_GRAPHS  1024
#define EMB       32
#define HID       64
#define N_CLASSES 10
#define SCAN_BLOCKS 391   // ceil(100000/256)
#define NCOMBO 153        // 17 shape ids x 9 color ids
#define BUCK_NODES 448    // nodes per dst-bucket
#define NBUCK 224         // ceil(100000/448)
#define BIN_CAP 8192      // per-bucket staging capacity (mean 7168, sigma ~85)
#define EPB 8192          // edges per binA block

// ---------------- prep: combo[v], per-graph counts ----------------
__global__ __launch_bounds__(256) void prep_kernel(
    const int* __restrict__ sid, const int* __restrict__ cid,
    const int* __restrict__ batch, int* __restrict__ combo, int* __restrict__ cnt) {
    int v = blockIdx.x * 256 + threadIdx.x;
    if (v < N_NODES) {
        combo[v] = sid[v] * 9 + cid[v];
        atomicAdd(&cnt[batch[v]], 1);
    }
}

// ---------------- combined table: TC[s*9+c][j] = (st[s]@W1)[j] + (ct[c]@W1)[j] ----------------
__global__ __launch_bounds__(64) void tc_kernel(
    const float* __restrict__ st, const float* __restrict__ ct,
    const float* __restrict__ W1, float* __restrict__ TC) {
    int r = blockIdx.x, j = threadIdx.x;
    int s = r / 9, c = r % 9;
    float acc = 0.0f;
    if (s != 0) {
#pragma unroll
        for (int k = 0; k < EMB; ++k) acc = fmaf(st[s * EMB + k], W1[k * HID + j], acc);
    }
    if (c != 0) {
#pragma unroll
        for (int k = 0; k < EMB; ++k) acc = fmaf(ct[c * EMB + k], W1[k * HID + j], acc);
    }
    TC[r * HID + j] = acc;
}

// ---------------- binA: block-local counting sort by dst-bucket, chunked flush ----------------
__global__ __launch_bounds__(512) void binA_kernel(
    const int* __restrict__ src, const int* __restrict__ dst,
    const int* __restrict__ combo, int* __restrict__ gcur,
    int2* __restrict__ gbin) {
    __shared__ int2 stg[EPB];            // 64 KB
    __shared__ int hist[NBUCK];
    __shared__ int base[NBUCK + 1];
    __shared__ int gstart[NBUCK];
    __shared__ int scanbuf[256];
    int t = threadIdx.x;
    int e0 = blockIdx.x * EPB;
    for (int i = t; i < NBUCK; i += 512) hist[i] = 0;
    __syncthreads();

    int2 myq[16];
    int mybo[16];
#pragma unroll
    for (int i = 0; i < 16; ++i) {
        int e = e0 + t + i * 512;
        if (e < N_EDGES) {
            int d = dst[e];
            int s = src[e];
            unsigned b = (unsigned)d / BUCK_NODES;
            int off = atomicAdd(&hist[b], 1);
            myq[i].x = s | (combo[s] << 17);
            myq[i].y = d;
            mybo[i] = (int)(b << 16) | off;
        } else {
            mybo[i] = -1;
        }
    }
    __syncthreads();

    int h = (t < NBUCK) ? hist[t] : 0;
    if (t < 256) scanbuf[t] = h;
    __syncthreads();
#pragma unroll
    for (int off = 1; off < 256; off <<= 1) {
        int x = (t < 256 && t >= off) ? scanbuf[t - off] : 0;
        __syncthreads();
        if (t < 256) scanbuf[t] += x;
        __syncthreads();
    }
    if (t < NBUCK) base[t] = scanbuf[t] - h;
    if (t == 0) base[NBUCK] = scanbuf[255];
    __syncthreads();
#pragma unroll
    for (int i = 0; i < 16; ++i) {
        if (mybo[i] >= 0) {
            int b = mybo[i] >> 16, off = mybo[i] & 0xFFFF;
            stg[base[b] + off] = myq[i];
        }
    }
    if (t < NBUCK) {
        int n = hist[t];
        gstart[t] = n ? atomicAdd(&gcur[t], n) : 0;
    }
    __syncthreads();
    int total = base[NBUCK];
    for (int i = t; i < total; i += 512) {
        int2 q = stg[i];
        unsigned b = (unsigned)q.y / BUCK_NODES;
        gbin[(size_t)b * BIN_CAP + gstart[b] + (i - base[b])] = q;
    }
}

// ---------------- degB: per-bucket degree count; dis = rsqrt(1+deg) ----------------
__global__ __launch_bounds__(256) void degB_kernel(
    const int2* __restrict__ gbin, const int* __restrict__ gcur,
    int* __restrict__ degi, float* __restrict__ dis) {
    __shared__ int curs[BUCK_NODES];
    int b = blockIdx.x, t = threadIdx.x;
    for (int i = t; i < BUCK_NODES; i += 256) curs[i] = 0;
    __syncthreads();
    int n = gcur[b];
    const int2* mybin = gbin + (size_t)b * BIN_CAP;
    for (int i = t; i < n; i += 256) {
        int2 q = mybin[i];
        atomicAdd(&curs[q.y - b * BUCK_NODES], 1);
    }
    __syncthreads();
    for (int i = t; i < BUCK_NODES; i += 256) {
        int v = b * BUCK_NODES + i;
        if (v < N_NODES) {
            int d = curs[i];
            degi[v] = d;
            dis[v] = rsqrtf(1.0f + (float)d);
        }
    }
}

// ---------------- 3-pass exclusive scan of degrees -> rowptr ----------------
__global__ __launch_bounds__(256) void scanA_kernel(const int* __restrict__ degi,
                                                    int* __restrict__ rowptr,
                                                    int* __restrict__ bsum) {
    __shared__ int s[256];
    int t = threadIdx.x, b = blockIdx.x;
    int v = b * 256 + t;
    int d = (v < N_NODES) ? degi[v] : 0;
    s[t] = d; __syncthreads();
#pragma unroll
    for (int off = 1; off < 256; off <<= 1) {
        int x = (t >= off) ? s[t - off] : 0;
        __syncthreads();
        s[t] += x;
        __syncthreads();
    }
    if (v < N_NODES) rowptr[v] = s[t] - d;
    if (t == 255) bsum[b] = s[255];
}

__global__ __launch_bounds__(512) void scanB_kernel(int* __restrict__ bsum) {
    __shared__ int s[512];
    int t = threadIdx.x;
    int d = (t < SCAN_BLOCKS) ? bsum[t] : 0;
    s[t] = d; __syncthreads();
#pragma unroll
    for (int off = 1; off < 512; off <<= 1) {
        int x = (t >= off) ? s[t - off] : 0;
        __syncthreads();
        s[t] += x;
        __syncthreads();
    }
    if (t < SCAN_BLOCKS) bsum[t] = s[t] - d;
}

__global__ __launch_bounds__(256) void scanC_kernel(int* __restrict__ rowptr,
                                                    const int* __restrict__ bsum) {
    int t = threadIdx.x, b = blockIdx.x;
    int v = b * 256 + t;
    if (v < N_NODES) rowptr[v] += bsum[b];
    if (b == 0 && t == 0) rowptr[N_NODES] = N_EDGES;
}

// ---------------- binB: per-bucket fine scatter to CSR ----------------
__global__ __launch_bounds__(256) void binB_kernel(
    const int2* __restrict__ gbin, const int* __restrict__ gcur,
    const int* __restrict__ rowptr, const float* __restrict__ dis,
    int2* __restrict__ epack) {
    __shared__ int curs[BUCK_NODES];
    int b = blockIdx.x, t = threadIdx.x;
    for (int i = t; i < BUCK_NODES; i += 256) curs[i] = 0;
    __syncthreads();
    int n = gcur[b];
    const int2* mybin = gbin + (size_t)b * BIN_CAP;
    for (int i = t; i < n; i += 256) {
        int2 q = mybin[i];
        int local = q.y - b * BUCK_NODES;
        int r = atomicAdd(&curs[local], 1);
        int2 rec;
        rec.x = q.x;
        rec.y = __float_as_int(dis[q.x & 0x1FFFF]);
        epack[rowptr[q.y] + r] = rec;
    }
}

// ---------------- layer-1 aggregate from combined table -> x1 ----------------
__global__ __launch_bounds__(256) void agg1_kernel(
    const int2* __restrict__ epack, const int* __restrict__ rowptr,
    const int* __restrict__ combo, const float* __restrict__ dis,
    const float* __restrict__ TC, const float* __restrict__ b1,
    float* __restrict__ x1) {
    __shared__ __align__(16) float TCs[NCOMBO * HID];   // 39,168 B
    int t = threadIdx.x;
    {
        const float4* s4 = (const float4*)TC;
        float4* d4 = (float4*)TCs;
        for (int i = t; i < NCOMBO * HID / 4; i += 256) d4[i] = s4[i];
    }
    __syncthreads();
    int lane = t & 63, w = t >> 6;
    float bias = b1[lane];
    int v0 = (blockIdx.x * 4 + w) * 4;
    for (int n = 0; n < 4; ++n) {
        int v = v0 + n;
        int e  = __builtin_amdgcn_readfirstlane(rowptr[v]);
        int e1 = __builtin_amdgcn_readfirstlane(rowptr[v + 1]);
        float acc = 0.0f;
        for (; e + 8 <= e1; e += 8) {
            int2 q[8];
#pragma unroll
            for (int i = 0; i < 8; ++i) q[i] = epack[e + i];
#pragma unroll
            for (int i = 0; i < 8; ++i)
                acc = fmaf(__int_as_float(q[i].y),
                           TCs[((unsigned)q[i].x >> 17) * HID + lane], acc);
        }
        for (; e < e1; ++e) {
            int2 q = epack[e];
            acc = fmaf(__int_as_float(q.y),
                       TCs[((unsigned)q.x >> 17) * HID + lane], acc);
        }
        float dv = dis[v];
        float hv = TCs[combo[v] * HID + lane];
        float val = dv * fmaf(hv, dv, acc) + bias;
        x1[(size_t)v * HID + lane] = val > 0.0f ? val : 0.0f;
    }
}

// ---------------- mm2: h2h = (x1 @ W2) in fp16; W2 column in 64 VGPRs ----------------
__global__ __launch_bounds__(256, 2) void mm2_kernel(const float* __restrict__ x,
                                                     const float* __restrict__ W2,
                                                     __half* __restrict__ h2h) {
    __shared__ __align__(16) float xs[4][HID];
    int t = threadIdx.x, lane = t & 63, w = t >> 6;
    float wcol[HID];
#pragma unroll
    for (int k = 0; k < HID; ++k) wcol[k] = W2[k * HID + lane];
    int v0 = (blockIdx.x * 4 + w) * 16;
    for (int n = 0; n < 16; ++n) {
        int v = v0 + n;
        if (v >= N_NODES) return;
        xs[w][lane] = x[(size_t)v * HID + lane];
        float acc = 0.0f;
#pragma unroll
        for (int k4 = 0; k4 < HID / 4; ++k4) {
            float4 xv = *(const float4*)(&xs[w][k4 * 4]);
            acc = fmaf(xv.x, wcol[k4 * 4 + 0], acc);
            acc = fmaf(xv.y, wcol[k4 * 4 + 1], acc);
            acc = fmaf(xv.z, wcol[k4 * 4 + 2], acc);
            acc = fmaf(xv.w, wcol[k4 * 4 + 3], acc);
        }
        h2h[(size_t)v * HID + lane] = __float2half_rn(acc);
    }
}

// ---------------- layer-2 aggregate + fused mean-pool (fp16 gather, 8 loads in flight) ----------------
__global__ __launch_bounds__(256) void agg2_pool_kernel(
    const int2* __restrict__ epack, const int* __restrict__ rowptr,
    const __half* __restrict__ h2h, const float* __restrict__ dis,
    const float* __restrict__ b2, const int* __restrict__ batch,
    float* __restrict__ pooled) {
    int t = threadIdx.x, lane = t & 63;
    int v = blockIdx.x * 4 + (t >> 6);
    int e  = __builtin_amdgcn_readfirstlane(rowptr[v]);
    int e1 = __builtin_amdgcn_readfirstlane(rowptr[v + 1]);
    float acc = 0.0f;
    for (; e + 8 <= e1; e += 8) {
        int2 q[8];
#pragma unroll
        for (int i = 0; i < 8; ++i) q[i] = epack[e + i];
        __half g[8];
#pragma unroll
        for (int i = 0; i < 8; ++i)
            g[i] = h2h[(size_t)(q[i].x & 0x1FFFF) * HID + lane];
#pragma unroll
        for (int i = 0; i < 8; ++i)
            acc = fmaf(__int_as_float(q[i].y), __half2float(g[i]), acc);
    }
    for (; e < e1; ++e) {
        int2 q = epack[e];
        acc = fmaf(__int_as_float(q.y),
                   __half2float(h2h[(size_t)(q.x & 0x1FFFF) * HID + lane]), acc);
    }
    float dv = dis[v];
    float self = __half2float(h2h[(size_t)v * HID + lane]);
    float val = dv * fmaf(self, dv, acc) + b2[lane];
    val = val > 0.0f ? val : 0.0f;
    unsafeAtomicAdd(&pooled[batch[v] * HID + lane], val);   // full-wave 256B atomic
}

// ---------------- logits ----------------
__global__ __launch_bounds__(64) void logits_kernel(
    const float* __restrict__ pooled, const int* __restrict__ cnt,
    const float* __restrict__ Wl, const float* __restrict__ bl,
    float* __restrict__ out) {
    __shared__ float row[HID];
    int g = blockIdx.x, t = threadIdx.x;
    int c = cnt[g]; if (c < 1) c = 1;
    row[t] = pooled[g * HID + t] / (float)c;
    __syncthreads();
    if (t < N_CLASSES) {
        float acc = bl[t];
#pragma unroll
        for (int k = 0; k < HID; ++k) acc = fmaf(row[k], Wl[k * N_CLASSES + t], acc);
        out[g * N_CLASSES + t] = acc;
    }
}

extern "C" void kernel_launch(void* const* d_in, const int* in_sizes, int n_in,
                              void* d_out, int out_size, void* d_ws, size_t ws_size,
                              hipStream_t stream) {
    const int*   shape_id = (const int*)d_in[0];
    const int*   color_id = (const int*)d_in[1];
    const int*   edge_idx = (const int*)d_in[2];
    const int*   batch    = (const int*)d_in[3];
    const float* st       = (const float*)d_in[4];
    const float* ct       = (const float*)d_in[5];
    const float* W1       = (const float*)d_in[6];
    const float* b1       = (const float*)d_in[7];
    const float* W2       = (const float*)d_in[8];
    const float* b2       = (const float*)d_in[9];
    const float* Wl       = (const float*)d_in[10];
    const float* bl       = (const float*)d_in[11];
    float* out = (float*)d_out;

    const int* src = edge_idx;
    const int* dst = edge_idx + N_EDGES;

    // workspace layout (aligned). gbin aliases x1 (dead until agg1).
    char* ws = (char*)d_ws;
    int*    combo  = (int*)   (ws + 0);            //   400,384 B
    float*  dis    = (float*) (ws + 400384);       //   400,384 B
    int*    degi   = (int*)   (ws + 800768);       //   400,384 B
    int*    rowptr = (int*)   (ws + 1201152);      //   400,384 B
    int*    bsum   = (int*)   (ws + 1601536);      //     2,048 B
    float*  TC     = (float*) (ws + 1603584);      //    39,424 B
    float*  pooled = (float*) (ws + 1643008);      //   262,144 B
    int*    cnt    = (int*)   (ws + 1905152);      //     4,096 B
    int*    gcur   = (int*)   (ws + 1909248);      //     1,024 B
    int2*   epack  = (int2*)  (ws + 1910272);      // 12,800,000 B
    float*  x1     = (float*) (ws + 14710272);     // 25,600,000 B
    __half* h2h    = (__half*)(ws + 40310272);     // 12,800,000 B (total ~53.1 MB)
    int2*   gbin   = (int2*)  x1;                  // alias: 224*8192*8 = 14.68 MB

    hipMemsetAsync(pooled, 0, N_GRAPHS * HID * sizeof(float) + N_GRAPHS * sizeof(int), stream);
    hipMemsetAsync(gcur, 0, NBUCK * sizeof(int), stream);

    // 1. per-node combo + per-graph counts
    prep_kernel<<<SCAN_BLOCKS, 256, 0, stream>>>(shape_id, color_id, batch, combo, cnt);

    // 2. combined (shape,color)->h1 table
    tc_kernel<<<NCOMBO, 64, 0, stream>>>(st, ct, W1, TC);

    // 3. bin edges by dst-bucket (chunked, coalesced writes)
    binA_kernel<<<(N_EDGES + EPB - 1) / EPB, 512, 0, stream>>>(src, dst, combo, gcur, gbin);

    // 4. per-bucket degree count + dis
    degB_kernel<<<NBUCK, 256, 0, stream>>>(gbin, gcur, degi, dis);

    // 5. exclusive scan -> rowptr
    scanA_kernel<<<SCAN_BLOCKS, 256, 0, stream>>>(degi, rowptr, bsum);
    scanB_kernel<<<1, 512, 0, stream>>>(bsum);
    scanC_kernel<<<SCAN_BLOCKS, 256, 0, stream>>>(rowptr, bsum);

    // 6. per-bucket scatter to CSR (single-XCD windows)
    binB_kernel<<<NBUCK, 256, 0, stream>>>(gbin, gcur, rowptr, dis, epack);

    // 7. layer-1 aggregate -> x1
    agg1_kernel<<<6250, 256, 0, stream>>>(epack, rowptr, combo, dis, TC, b1, x1);

    // 8. h2 (fp16) = x1 @ W2
    mm2_kernel<<<1563, 256, 0, stream>>>(x1, W2, h2h);

    // 9. layer-2 aggregate + pool (fp16 gather, R6 loop structure)
    agg2_pool_kernel<<<N_NODES / 4, 256, 0, stream>>>(epack, rowptr, h2h, dis, b2,
                                                      batch, pooled);

    // 10. logits
    logits_kernel<<<N_GRAPHS, 64, 0, stream>>>(pooled, cnt, Wl, bl, out);
}

// Round 10
// 315.187 us; speedup vs baseline: 1.2466x; 1.0215x over previous
//
#include <hip/hip_runtime.h>
#include <hip/hip_bf16.h>
#include <hip/hip_fp16.h>

#define N_NODES   100000
#define N_EDGES   1600000
#define N_GRAPHS  1024
#define EMB       32
#define HID       64
#define N_CLASSES 10
#define SCAN_BLOCKS 391   // ceil(100000/256)
#define NCOMBO 153        // 17 shape ids x 9 color ids
#define BUCK_NODES 448    // nodes per dst-bucket
#define NBUCK 224         // ceil(100000/448)
#define BIN_CAP 8192      // per-bucket staging capacity (mean 7143, +12 sigma)
#define EPB 8192          // edges per binA block

// ---------------- prep: combo[v], per-graph counts ----------------
__global__ __launch_bounds__(256) void prep_kernel(
    const int* __restrict__ sid, const int* __restrict__ cid,
    const int* __restrict__ batch, int* __restrict__ combo, int* __restrict__ cnt) {
    int v = blockIdx.x * 256 + threadIdx.x;
    if (v < N_NODES) {
        combo[v] = sid[v] * 9 + cid[v];
        atomicAdd(&cnt[batch[v]], 1);
    }
}

// ---------------- combined table: TC[s*9+c][j] = (st[s]@W1)[j] + (ct[c]@W1)[j] ----------------
__global__ __launch_bounds__(64) void tc_kernel(
    const float* __restrict__ st, const float* __restrict__ ct,
    const float* __restrict__ W1, float* __restrict__ TC) {
    int r = blockIdx.x, j = threadIdx.x;
    int s = r / 9, c = r % 9;
    float acc = 0.0f;
    if (s != 0) {
#pragma unroll
        for (int k = 0; k < EMB; ++k) acc = fmaf(st[s * EMB + k], W1[k * HID + j], acc);
    }
    if (c != 0) {
#pragma unroll
        for (int k = 0; k < EMB; ++k) acc = fmaf(ct[c * EMB + k], W1[k * HID + j], acc);
    }
    TC[r * HID + j] = acc;
}

// ---------------- binA: block-local counting sort by dst-bucket, chunked flush ----------------
__global__ __launch_bounds__(512) void binA_kernel(
    const int* __restrict__ src, const int* __restrict__ dst,
    const int* __restrict__ combo, int* __restrict__ gcur,
    int2* __restrict__ gbin) {
    __shared__ int2 stg[EPB];            // 64 KB
    __shared__ int hist[NBUCK];
    __shared__ int base[NBUCK + 1];
    __shared__ int gstart[NBUCK];
    __shared__ int scanbuf[256];
    int t = threadIdx.x;
    int e0 = blockIdx.x * EPB;
    for (int i = t; i < NBUCK; i += 512) hist[i] = 0;
    __syncthreads();

    int2 myq[16];
    int mybo[16];
#pragma unroll
    for (int i = 0; i < 16; ++i) {
        int e = e0 + t + i * 512;
        if (e < N_EDGES) {
            int d = dst[e];
            int s = src[e];
            unsigned b = (unsigned)d / BUCK_NODES;
            int off = atomicAdd(&hist[b], 1);
            myq[i].x = s | (combo[s] << 17);
            myq[i].y = d;
            mybo[i] = (int)(b << 16) | off;
        } else {
            mybo[i] = -1;
        }
    }
    __syncthreads();

    int h = (t < NBUCK) ? hist[t] : 0;
    if (t < 256) scanbuf[t] = h;
    __syncthreads();
#pragma unroll
    for (int off = 1; off < 256; off <<= 1) {
        int x = (t < 256 && t >= off) ? scanbuf[t - off] : 0;
        __syncthreads();
        if (t < 256) scanbuf[t] += x;
        __syncthreads();
    }
    if (t < NBUCK) base[t] = scanbuf[t] - h;
    if (t == 0) base[NBUCK] = scanbuf[255];
    __syncthreads();
#pragma unroll
    for (int i = 0; i < 16; ++i) {
        if (mybo[i] >= 0) {
            int b = mybo[i] >> 16, off = mybo[i] & 0xFFFF;
            stg[base[b] + off] = myq[i];
        }
    }
    if (t < NBUCK) {
        int n = hist[t];
        gstart[t] = n ? atomicAdd(&gcur[t], n) : 0;
    }
    __syncthreads();
    int total = base[NBUCK];
    for (int i = t; i < total; i += 512) {
        int2 q = stg[i];
        unsigned b = (unsigned)q.y / BUCK_NODES;
        gbin[(size_t)b * BIN_CAP + gstart[b] + (i - base[b])] = q;
    }
}

// ---------------- degB: per-bucket degree count; dis = rsqrt(1+deg) ----------------
__global__ __launch_bounds__(256) void degB_kernel(
    const int2* __restrict__ gbin, const int* __restrict__ gcur,
    int* __restrict__ degi, float* __restrict__ dis) {
    __shared__ int curs[BUCK_NODES];
    int b = blockIdx.x, t = threadIdx.x;
    for (int i = t; i < BUCK_NODES; i += 256) curs[i] = 0;
    __syncthreads();
    int n = gcur[b];
    const int2* mybin = gbin + (size_t)b * BIN_CAP;
    for (int i = t; i < n; i += 256) {
        int2 q = mybin[i];
        atomicAdd(&curs[q.y - b * BUCK_NODES], 1);
    }
    __syncthreads();
    for (int i = t; i < BUCK_NODES; i += 256) {
        int v = b * BUCK_NODES + i;
        if (v < N_NODES) {
            int d = curs[i];
            degi[v] = d;
            dis[v] = rsqrtf(1.0f + (float)d);
        }
    }
}

// ---------------- 3-pass exclusive scan of degrees -> rowptr ----------------
__global__ __launch_bounds__(256) void scanA_kernel(const int* __restrict__ degi,
                                                    int* __restrict__ rowptr,
                                                    int* __restrict__ bsum) {
    __shared__ int s[256];
    int t = threadIdx.x, b = blockIdx.x;
    int v = b * 256 + t;
    int d = (v < N_NODES) ? degi[v] : 0;
    s[t] = d; __syncthreads();
#pragma unroll
    for (int off = 1; off < 256; off <<= 1) {
        int x = (t >= off) ? s[t - off] : 0;
        __syncthreads();
        s[t] += x;
        __syncthreads();
    }
    if (v < N_NODES) rowptr[v] = s[t] - d;
    if (t == 255) bsum[b] = s[255];
}

__global__ __launch_bounds__(512) void scanB_kernel(int* __restrict__ bsum) {
    __shared__ int s[512];
    int t = threadIdx.x;
    int d = (t < SCAN_BLOCKS) ? bsum[t] : 0;
    s[t] = d; __syncthreads();
#pragma unroll
    for (int off = 1; off < 512; off <<= 1) {
        int x = (t >= off) ? s[t - off] : 0;
        __syncthreads();
        s[t] += x;
        __syncthreads();
    }
    if (t < SCAN_BLOCKS) bsum[t] = s[t] - d;
}

__global__ __launch_bounds__(256) void scanC_kernel(int* __restrict__ rowptr,
                                                    const int* __restrict__ bsum) {
    int t = threadIdx.x, b = blockIdx.x;
    int v = b * 256 + t;
    if (v < N_NODES) rowptr[v] += bsum[b];
    if (b == 0 && t == 0) rowptr[N_NODES] = N_EDGES;
}

// ---------------- binB: per-bucket fine scatter to CSR ----------------
__global__ __launch_bounds__(256) void binB_kernel(
    const int2* __restrict__ gbin, const int* __restrict__ gcur,
    const int* __restrict__ rowptr, const float* __restrict__ dis,
    int2* __restrict__ epack) {
    __shared__ int curs[BUCK_NODES];
    int b = blockIdx.x, t = threadIdx.x;
    for (int i = t; i < BUCK_NODES; i += 256) curs[i] = 0;
    __syncthreads();
    int n = gcur[b];
    const int2* mybin = gbin + (size_t)b * BIN_CAP;
    for (int i = t; i < n; i += 256) {
        int2 q = mybin[i];
        int local = q.y - b * BUCK_NODES;
        int r = atomicAdd(&curs[local], 1);
        int2 rec;
        rec.x = q.x;
        rec.y = __float_as_int(dis[q.x & 0x1FFFF]);
        epack[rowptr[q.y] + r] = rec;
    }
}

// ---------------- layer-1 aggregate from combined table -> x1 ----------------
__global__ __launch_bounds__(256) void agg1_kernel(
    const int2* __restrict__ epack, const int* __restrict__ rowptr,
    const int* __restrict__ combo, const float* __restrict__ dis,
    const float* __restrict__ TC, const float* __restrict__ b1,
    float* __restrict__ x1) {
    __shared__ __align__(16) float TCs[NCOMBO * HID];   // 39,168 B
    int t = threadIdx.x;
    {
        const float4* s4 = (const float4*)TC;
        float4* d4 = (float4*)TCs;
        for (int i = t; i < NCOMBO * HID / 4; i += 256) d4[i] = s4[i];
    }
    __syncthreads();
    int lane = t & 63, w = t >> 6;
    float bias = b1[lane];
    int v0 = (blockIdx.x * 4 + w) * 4;
    for (int n = 0; n < 4; ++n) {
        int v = v0 + n;
        int e  = __builtin_amdgcn_readfirstlane(rowptr[v]);
        int e1 = __builtin_amdgcn_readfirstlane(rowptr[v + 1]);
        float acc = 0.0f;
        for (; e + 8 <= e1; e += 8) {
            int2 q[8];
#pragma unroll
            for (int i = 0; i < 8; ++i) q[i] = epack[e + i];
#pragma unroll
            for (int i = 0; i < 8; ++i)
                acc = fmaf(__int_as_float(q[i].y),
                           TCs[((unsigned)q[i].x >> 17) * HID + lane], acc);
        }
        for (; e < e1; ++e) {
            int2 q = epack[e];
            acc = fmaf(__int_as_float(q.y),
                       TCs[((unsigned)q.x >> 17) * HID + lane], acc);
        }
        float dv = dis[v];
        float hv = TCs[combo[v] * HID + lane];
        float val = dv * fmaf(hv, dv, acc) + bias;
        x1[(size_t)v * HID + lane] = val > 0.0f ? val : 0.0f;
    }
}

// ---------------- mm2: h2h = (x1 @ W2) in fp16; W2 column in 64 VGPRs ----------------
__global__ __launch_bounds__(256, 2) void mm2_kernel(const float* __restrict__ x,
                                                     const float* __restrict__ W2,
                                                     __half* __restrict__ h2h) {
    __shared__ __align__(16) float xs[4][HID];
    int t = threadIdx.x, lane = t & 63, w = t >> 6;
    float wcol[HID];
#pragma unroll
    for (int k = 0; k < HID; ++k) wcol[k] = W2[k * HID + lane];
    int v0 = (blockIdx.x * 4 + w) * 16;
    for (int n = 0; n < 16; ++n) {
        int v = v0 + n;
        if (v >= N_NODES) return;
        xs[w][lane] = x[(size_t)v * HID + lane];
        float acc = 0.0f;
#pragma unroll
        for (int k4 = 0; k4 < HID / 4; ++k4) {
            float4 xv = *(const float4*)(&xs[w][k4 * 4]);
            acc = fmaf(xv.x, wcol[k4 * 4 + 0], acc);
            acc = fmaf(xv.y, wcol[k4 * 4 + 1], acc);
            acc = fmaf(xv.z, wcol[k4 * 4 + 2], acc);
            acc = fmaf(xv.w, wcol[k4 * 4 + 3], acc);
        }
        h2h[(size_t)v * HID + lane] = __float2half_rn(acc);
    }
}

// ---------------- layer-2 aggregate + pool: paired nodes, 16 gathers in flight ----------------
__global__ __launch_bounds__(256) void agg2_pool_kernel(
    const int2* __restrict__ epack, const int* __restrict__ rowptr,
    const __half* __restrict__ h2h, const float* __restrict__ dis,
    const float* __restrict__ b2, const int* __restrict__ batch,
    float* __restrict__ pooled) {
    int t = threadIdx.x, lane = t & 63, w = t >> 6;
    int vA = (blockIdx.x * 4 + w) * 2;      // grid 12500: vA,vB always < N_NODES
    int vB = vA + 1;
    int eA = __builtin_amdgcn_readfirstlane(rowptr[vA]);
    int mA = __builtin_amdgcn_readfirstlane(rowptr[vA + 1]);
    int eB = mA;
    int mB = __builtin_amdgcn_readfirstlane(rowptr[vB + 1]);
    float accA = 0.0f, accB = 0.0f;
    // paired phase: two 8-deep gather pipelines in flight
    while (eA + 8 <= mA && eB + 8 <= mB) {
        int2 qA[8], qB[8];
#pragma unroll
        for (int i = 0; i < 8; ++i) { qA[i] = epack[eA + i]; qB[i] = epack[eB + i]; }
        __half gA[8], gB[8];
#pragma unroll
        for (int i = 0; i < 8; ++i) {
            gA[i] = h2h[(size_t)(qA[i].x & 0x1FFFF) * HID + lane];
            gB[i] = h2h[(size_t)(qB[i].x & 0x1FFFF) * HID + lane];
        }
#pragma unroll
        for (int i = 0; i < 8; ++i) {
            accA = fmaf(__int_as_float(qA[i].y), __half2float(gA[i]), accA);
            accB = fmaf(__int_as_float(qB[i].y), __half2float(gB[i]), accB);
        }
        eA += 8; eB += 8;
    }
    // drain A
    for (; eA + 8 <= mA; eA += 8) {
        int2 q[8];
#pragma unroll
        for (int i = 0; i < 8; ++i) q[i] = epack[eA + i];
        __half g[8];
#pragma unroll
        for (int i = 0; i < 8; ++i) g[i] = h2h[(size_t)(q[i].x & 0x1FFFF) * HID + lane];
#pragma unroll
        for (int i = 0; i < 8; ++i) accA = fmaf(__int_as_float(q[i].y), __half2float(g[i]), accA);
    }
    for (; eA < mA; ++eA) {
        int2 q = epack[eA];
        accA = fmaf(__int_as_float(q.y), __half2float(h2h[(size_t)(q.x & 0x1FFFF) * HID + lane]), accA);
    }
    // drain B
    for (; eB + 8 <= mB; eB += 8) {
        int2 q[8];
#pragma unroll
        for (int i = 0; i < 8; ++i) q[i] = epack[eB + i];
        __half g[8];
#pragma unroll
        for (int i = 0; i < 8; ++i) g[i] = h2h[(size_t)(q[i].x & 0x1FFFF) * HID + lane];
#pragma unroll
        for (int i = 0; i < 8; ++i) accB = fmaf(__int_as_float(q[i].y), __half2float(g[i]), accB);
    }
    for (; eB < mB; ++eB) {
        int2 q = epack[eB];
        accB = fmaf(__int_as_float(q.y), __half2float(h2h[(size_t)(q.x & 0x1FFFF) * HID + lane]), accB);
    }
    float bv = b2[lane];
    {
        float dv = dis[vA];
        float self = __half2float(h2h[(size_t)vA * HID + lane]);
        float val = dv * fmaf(self, dv, accA) + bv;
        val = val > 0.0f ? val : 0.0f;
        unsafeAtomicAdd(&pooled[batch[vA] * HID + lane], val);
    }
    {
        float dv = dis[vB];
        float self = __half2float(h2h[(size_t)vB * HID + lane]);
        float val = dv * fmaf(self, dv, accB) + bv;
        val = val > 0.0f ? val : 0.0f;
        unsafeAtomicAdd(&pooled[batch[vB] * HID + lane], val);
    }
}

// ---------------- logits ----------------
__global__ __launch_bounds__(64) void logits_kernel(
    const float* __restrict__ pooled, const int* __restrict__ cnt,
    const float* __restrict__ Wl, const float* __restrict__ bl,
    float* __restrict__ out) {
    __shared__ float row[HID];
    int g = blockIdx.x, t = threadIdx.x;
    int c = cnt[g]; if (c < 1) c = 1;
    row[t] = pooled[g * HID + t] / (float)c;
    __syncthreads();
    if (t < N_CLASSES) {
        float acc = bl[t];
#pragma unroll
        for (int k = 0; k < HID; ++k) acc = fmaf(row[k], Wl[k * N_CLASSES + t], acc);
        out[g * N_CLASSES + t] = acc;
    }
}

extern "C" void kernel_launch(void* const* d_in, const int* in_sizes, int n_in,
                              void* d_out, int out_size, void* d_ws, size_t ws_size,
                              hipStream_t stream) {
    const int*   shape_id = (const int*)d_in[0];
    const int*   color_id = (const int*)d_in[1];
    const int*   edge_idx = (const int*)d_in[2];
    const int*   batch    = (const int*)d_in[3];
    const float* st       = (const float*)d_in[4];
    const float* ct       = (const float*)d_in[5];
    const float* W1       = (const float*)d_in[6];
    const float* b1       = (const float*)d_in[7];
    const float* W2       = (const float*)d_in[8];
    const float* b2       = (const float*)d_in[9];
    const float* Wl       = (const float*)d_in[10];
    const float* bl       = (const float*)d_in[11];
    float* out = (float*)d_out;

    const int* src = edge_idx;
    const int* dst = edge_idx + N_EDGES;

    // workspace layout (aligned). gbin aliases x1 (dead until agg1). [R8-identical]
    char* ws = (char*)d_ws;
    int*    combo  = (int*)   (ws + 0);            //   400,384 B
    float*  dis    = (float*) (ws + 400384);       //   400,384 B
    int*    degi   = (int*)   (ws + 800768);       //   400,384 B
    int*    rowptr = (int*)   (ws + 1201152);      //   400,384 B
    int*    bsum   = (int*)   (ws + 1601536);      //     2,048 B
    float*  TC     = (float*) (ws + 1603584);      //    39,424 B
    float*  pooled = (float*) (ws + 1643008);      //   262,144 B
    int*    cnt    = (int*)   (ws + 1905152);      //     4,096 B
    int*    gcur   = (int*)   (ws + 1909248);      //     1,024 B
    int2*   epack  = (int2*)  (ws + 1910272);      // 12,800,000 B
    float*  x1     = (float*) (ws + 14710272);     // 25,600,000 B
    __half* h2h    = (__half*)(ws + 40310272);     // 12,800,000 B (total ~53.1 MB)
    int2*   gbin   = (int2*)  x1;                  // alias: 224*8192*8 = 14.68 MB

    hipMemsetAsync(pooled, 0, N_GRAPHS * HID * sizeof(float) + N_GRAPHS * sizeof(int), stream);
    hipMemsetAsync(gcur, 0, NBUCK * sizeof(int), stream);

    // 1. per-node combo + per-graph counts
    prep_kernel<<<SCAN_BLOCKS, 256, 0, stream>>>(shape_id, color_id, batch, combo, cnt);

    // 2. combined (shape,color)->h1 table
    tc_kernel<<<NCOMBO, 64, 0, stream>>>(st, ct, W1, TC);

    // 3. bin edges by dst-bucket (chunked, coalesced writes)
    binA_kernel<<<(N_EDGES + EPB - 1) / EPB, 512, 0, stream>>>(src, dst, combo, gcur, gbin);

    // 4. per-bucket degree count + dis
    degB_kernel<<<NBUCK, 256, 0, stream>>>(gbin, gcur, degi, dis);

    // 5. exclusive scan -> rowptr
    scanA_kernel<<<SCAN_BLOCKS, 256, 0, stream>>>(degi, rowptr, bsum);
    scanB_kernel<<<1, 512, 0, stream>>>(bsum);
    scanC_kernel<<<SCAN_BLOCKS, 256, 0, stream>>>(rowptr, bsum);

    // 6. per-bucket scatter to CSR (single-XCD windows)
    binB_kernel<<<NBUCK, 256, 0, stream>>>(gbin, gcur, rowptr, dis, epack);

    // 7. layer-1 aggregate -> x1
    agg1_kernel<<<6250, 256, 0, stream>>>(epack, rowptr, combo, dis, TC, b1, x1);

    // 8. h2 (fp16) = x1 @ W2
    mm2_kernel<<<1563, 256, 0, stream>>>(x1, W2, h2h);

    // 9. layer-2 aggregate + pool (paired nodes, 16 gathers in flight)
    agg2_pool_kernel<<<N_NODES / 8, 256, 0, stream>>>(epack, rowptr, h2h, dis, b2,
                                                      batch, pooled);

    // 10. logits
    logits_kernel<<<N_GRAPHS, 64, 0, stream>>>(pooled, cnt, Wl, bl, out);
}

// Round 11
// 310.652 us; speedup vs baseline: 1.2648x; 1.0146x over previous
//
#include <hip/hip_runtime.h>
#include <hip/hip_bf16.h>
#include <hip/hip_fp16.h>

#define N_NODES   100000
#define N_EDGES   1600000
#define N_GRAPHS  1024
#define EMB       32
#define HID       64
#define N_CLASSES 10
#define SCAN_BLOCKS 391   // ceil(100000/256)
#define NCOMBO 153        // 17 shape ids x 9 color ids
#define BUCK_NODES 448    // nodes per dst-bucket
#define NBUCK 224         // ceil(100000/448)
#define BIN_CAP 8192      // per-bucket staging capacity (mean 7143, +12 sigma)
#define EPB 8192          // edges per binA block

// ---------------- prep: combo[v], per-graph counts ----------------
__global__ __launch_bounds__(256) void prep_kernel(
    const int* __restrict__ sid, const int* __restrict__ cid,
    const int* __restrict__ batch, int* __restrict__ combo, int* __restrict__ cnt) {
    int v = blockIdx.x * 256 + threadIdx.x;
    if (v < N_NODES) {
        combo[v] = sid[v] * 9 + cid[v];
        atomicAdd(&cnt[batch[v]], 1);
    }
}

// ---------------- combined table: TC[s*9+c][j] = (st[s]@W1)[j] + (ct[c]@W1)[j] ----------------
__global__ __launch_bounds__(64) void tc_kernel(
    const float* __restrict__ st, const float* __restrict__ ct,
    const float* __restrict__ W1, float* __restrict__ TC) {
    int r = blockIdx.x, j = threadIdx.x;
    int s = r / 9, c = r % 9;
    float acc = 0.0f;
    if (s != 0) {
#pragma unroll
        for (int k = 0; k < EMB; ++k) acc = fmaf(st[s * EMB + k], W1[k * HID + j], acc);
    }
    if (c != 0) {
#pragma unroll
        for (int k = 0; k < EMB; ++k) acc = fmaf(ct[c * EMB + k], W1[k * HID + j], acc);
    }
    TC[r * HID + j] = acc;
}

// ---------------- binA: block-local counting sort by dst-bucket, chunked flush ----------------
__global__ __launch_bounds__(512) void binA_kernel(
    const int* __restrict__ src, const int* __restrict__ dst,
    const int* __restrict__ combo, int* __restrict__ gcur,
    int2* __restrict__ gbin) {
    __shared__ int2 stg[EPB];            // 64 KB
    __shared__ int hist[NBUCK];
    __shared__ int base[NBUCK + 1];
    __shared__ int gstart[NBUCK];
    __shared__ int scanbuf[256];
    int t = threadIdx.x;
    int e0 = blockIdx.x * EPB;
    for (int i = t; i < NBUCK; i += 512) hist[i] = 0;
    __syncthreads();

    int2 myq[16];
    int mybo[16];
#pragma unroll
    for (int i = 0; i < 16; ++i) {
        int e = e0 + t + i * 512;
        if (e < N_EDGES) {
            int d = dst[e];
            int s = src[e];
            unsigned b = (unsigned)d / BUCK_NODES;
            int off = atomicAdd(&hist[b], 1);
            myq[i].x = s | (combo[s] << 17);
            myq[i].y = d;
            mybo[i] = (int)(b << 16) | off;
        } else {
            mybo[i] = -1;
        }
    }
    __syncthreads();

    int h = (t < NBUCK) ? hist[t] : 0;
    if (t < 256) scanbuf[t] = h;
    __syncthreads();
#pragma unroll
    for (int off = 1; off < 256; off <<= 1) {
        int x = (t < 256 && t >= off) ? scanbuf[t - off] : 0;
        __syncthreads();
        if (t < 256) scanbuf[t] += x;
        __syncthreads();
    }
    if (t < NBUCK) base[t] = scanbuf[t] - h;
    if (t == 0) base[NBUCK] = scanbuf[255];
    __syncthreads();
#pragma unroll
    for (int i = 0; i < 16; ++i) {
        if (mybo[i] >= 0) {
            int b = mybo[i] >> 16, off = mybo[i] & 0xFFFF;
            stg[base[b] + off] = myq[i];
        }
    }
    if (t < NBUCK) {
        int n = hist[t];
        gstart[t] = n ? atomicAdd(&gcur[t], n) : 0;
    }
    __syncthreads();
    int total = base[NBUCK];
    for (int i = t; i < total; i += 512) {
        int2 q = stg[i];
        unsigned b = (unsigned)q.y / BUCK_NODES;
        gbin[(size_t)b * BIN_CAP + gstart[b] + (i - base[b])] = q;
    }
}

// ---------------- degB: per-bucket degree count; dis = rsqrt(1+deg) ----------------
__global__ __launch_bounds__(256) void degB_kernel(
    const int2* __restrict__ gbin, const int* __restrict__ gcur,
    int* __restrict__ degi, float* __restrict__ dis) {
    __shared__ int curs[BUCK_NODES];
    int b = blockIdx.x, t = threadIdx.x;
    for (int i = t; i < BUCK_NODES; i += 256) curs[i] = 0;
    __syncthreads();
    int n = gcur[b];
    const int2* mybin = gbin + (size_t)b * BIN_CAP;
    for (int i = t; i < n; i += 256) {
        int2 q = mybin[i];
        atomicAdd(&curs[q.y - b * BUCK_NODES], 1);
    }
    __syncthreads();
    for (int i = t; i < BUCK_NODES; i += 256) {
        int v = b * BUCK_NODES + i;
        if (v < N_NODES) {
            int d = curs[i];
            degi[v] = d;
            dis[v] = rsqrtf(1.0f + (float)d);
        }
    }
}

// ---------------- 3-pass exclusive scan of degrees -> rowptr ----------------
__global__ __launch_bounds__(256) void scanA_kernel(const int* __restrict__ degi,
                                                    int* __restrict__ rowptr,
                                                    int* __restrict__ bsum) {
    __shared__ int s[256];
    int t = threadIdx.x, b = blockIdx.x;
    int v = b * 256 + t;
    int d = (v < N_NODES) ? degi[v] : 0;
    s[t] = d; __syncthreads();
#pragma unroll
    for (int off = 1; off < 256; off <<= 1) {
        int x = (t >= off) ? s[t - off] : 0;
        __syncthreads();
        s[t] += x;
        __syncthreads();
    }
    if (v < N_NODES) rowptr[v] = s[t] - d;
    if (t == 255) bsum[b] = s[255];
}

__global__ __launch_bounds__(512) void scanB_kernel(int* __restrict__ bsum) {
    __shared__ int s[512];
    int t = threadIdx.x;
    int d = (t < SCAN_BLOCKS) ? bsum[t] : 0;
    s[t] = d; __syncthreads();
#pragma unroll
    for (int off = 1; off < 512; off <<= 1) {
        int x = (t >= off) ? s[t - off] : 0;
        __syncthreads();
        s[t] += x;
        __syncthreads();
    }
    if (t < SCAN_BLOCKS) bsum[t] = s[t] - d;
}

__global__ __launch_bounds__(256) void scanC_kernel(int* __restrict__ rowptr,
                                                    const int* __restrict__ bsum) {
    int t = threadIdx.x, b = blockIdx.x;
    int v = b * 256 + t;
    if (v < N_NODES) rowptr[v] += bsum[b];
    if (b == 0 && t == 0) rowptr[N_NODES] = N_EDGES;
}

// ---------------- binB: per-bucket fine scatter to CSR ----------------
__global__ __launch_bounds__(256) void binB_kernel(
    const int2* __restrict__ gbin, const int* __restrict__ gcur,
    const int* __restrict__ rowptr, const float* __restrict__ dis,
    int2* __restrict__ epack) {
    __shared__ int curs[BUCK_NODES];
    int b = blockIdx.x, t = threadIdx.x;
    for (int i = t; i < BUCK_NODES; i += 256) curs[i] = 0;
    __syncthreads();
    int n = gcur[b];
    const int2* mybin = gbin + (size_t)b * BIN_CAP;
    for (int i = t; i < n; i += 256) {
        int2 q = mybin[i];
        int local = q.y - b * BUCK_NODES;
        int r = atomicAdd(&curs[local], 1);
        int2 rec;
        rec.x = q.x;
        rec.y = __float_as_int(dis[q.x & 0x1FFFF]);
        epack[rowptr[q.y] + r] = rec;
    }
}

// ---------------- fused layer-1 aggregate + mm2: h2s = (x1 @ W2) * dis[v], fp16 ----------------
// 4 waves/block, 4 nodes/wave. Edge agg from TC table (LDS), then wcol-register
// matmul via per-wave LDS row broadcast (verified mm2 pattern). LDS 40.2 KB ->
// 4 blocks/CU; wcol[64] + 8-deep edge staging ~110 VGPR.
__global__ __launch_bounds__(256) void agg1_mm2_kernel(
    const int2* __restrict__ epack, const int* __restrict__ rowptr,
    const int* __restrict__ combo, const float* __restrict__ dis,
    const float* __restrict__ TC, const float* __restrict__ W2,
    const float* __restrict__ b1, __half* __restrict__ h2s) {
    __shared__ __align__(16) float TCs[NCOMBO * HID];   // 39,168 B
    __shared__ __align__(16) float xs[4][HID];          //  1,024 B
    int t = threadIdx.x;
    {
        const float4* s4 = (const float4*)TC;
        float4* d4 = (float4*)TCs;
        for (int i = t; i < NCOMBO * HID / 4; i += 256) d4[i] = s4[i];
    }
    __syncthreads();
    int lane = t & 63, w = t >> 6;
    float bias = b1[lane];
    float wcol[HID];
#pragma unroll
    for (int k = 0; k < HID; ++k) wcol[k] = W2[k * HID + lane];
    int v0 = (blockIdx.x * 4 + w) * 4;
    for (int n = 0; n < 4; ++n) {
        int v = v0 + n;
        int e  = __builtin_amdgcn_readfirstlane(rowptr[v]);
        int e1 = __builtin_amdgcn_readfirstlane(rowptr[v + 1]);
        float acc = 0.0f;
        for (; e + 8 <= e1; e += 8) {
            int2 q[8];
#pragma unroll
            for (int i = 0; i < 8; ++i) q[i] = epack[e + i];
#pragma unroll
            for (int i = 0; i < 8; ++i)
                acc = fmaf(__int_as_float(q[i].y),
                           TCs[((unsigned)q[i].x >> 17) * HID + lane], acc);
        }
        for (; e < e1; ++e) {
            int2 q = epack[e];
            acc = fmaf(__int_as_float(q.y),
                       TCs[((unsigned)q.x >> 17) * HID + lane], acc);
        }
        float dv = dis[v];
        float hv = TCs[combo[v] * HID + lane];
        float val = dv * fmaf(hv, dv, acc) + bias;
        val = val > 0.0f ? val : 0.0f;              // x1[v][lane]

        // h2s[v][lane] = (sum_k x1[v][k] * W2[k][lane]) * dis[v]
        xs[w][lane] = val;                          // wave-coherent staging
        float acc2 = 0.0f;
#pragma unroll
        for (int k4 = 0; k4 < HID / 4; ++k4) {
            float4 xv = *(const float4*)(&xs[w][k4 * 4]);   // broadcast read
            acc2 = fmaf(xv.x, wcol[k4 * 4 + 0], acc2);
            acc2 = fmaf(xv.y, wcol[k4 * 4 + 1], acc2);
            acc2 = fmaf(xv.z, wcol[k4 * 4 + 2], acc2);
            acc2 = fmaf(xv.w, wcol[k4 * 4 + 3], acc2);
        }
        h2s[(size_t)v * HID + lane] = __float2half_rn(acc2 * dv);
    }
}

// ---------------- layer-2 aggregate + pool: paired nodes, prescaled h2s ----------------
// h2s[src] = h2[src]*dis[src], so per-edge contribution is just the gather value.
__global__ __launch_bounds__(256) void agg2_pool_kernel(
    const int2* __restrict__ epack, const int* __restrict__ rowptr,
    const __half* __restrict__ h2s, const float* __restrict__ dis,
    const float* __restrict__ b2, const int* __restrict__ batch,
    float* __restrict__ pooled) {
    int t = threadIdx.x, lane = t & 63, w = t >> 6;
    int vA = (blockIdx.x * 4 + w) * 2;      // grid 12500: vA,vB always < N_NODES
    int vB = vA + 1;
    int eA = __builtin_amdgcn_readfirstlane(rowptr[vA]);
    int mA = __builtin_amdgcn_readfirstlane(rowptr[vA + 1]);
    int eB = mA;
    int mB = __builtin_amdgcn_readfirstlane(rowptr[vB + 1]);
    float accA = 0.0f, accB = 0.0f;
    // paired phase: two 8-deep gather pipelines in flight
    while (eA + 8 <= mA && eB + 8 <= mB) {
        int2 qA[8], qB[8];
#pragma unroll
        for (int i = 0; i < 8; ++i) { qA[i] = epack[eA + i]; qB[i] = epack[eB + i]; }
        __half gA[8], gB[8];
#pragma unroll
        for (int i = 0; i < 8; ++i) {
            gA[i] = h2s[(size_t)(qA[i].x & 0x1FFFF) * HID + lane];
            gB[i] = h2s[(size_t)(qB[i].x & 0x1FFFF) * HID + lane];
        }
#pragma unroll
        for (int i = 0; i < 8; ++i) {
            accA += __half2float(gA[i]);
            accB += __half2float(gB[i]);
        }
        eA += 8; eB += 8;
    }
    // drain A
    for (; eA + 8 <= mA; eA += 8) {
        int2 q[8];
#pragma unroll
        for (int i = 0; i < 8; ++i) q[i] = epack[eA + i];
        __half g[8];
#pragma unroll
        for (int i = 0; i < 8; ++i) g[i] = h2s[(size_t)(q[i].x & 0x1FFFF) * HID + lane];
#pragma unroll
        for (int i = 0; i < 8; ++i) accA += __half2float(g[i]);
    }
    for (; eA < mA; ++eA) {
        int2 q = epack[eA];
        accA += __half2float(h2s[(size_t)(q.x & 0x1FFFF) * HID + lane]);
    }
    // drain B
    for (; eB + 8 <= mB; eB += 8) {
        int2 q[8];
#pragma unroll
        for (int i = 0; i < 8; ++i) q[i] = epack[eB + i];
        __half g[8];
#pragma unroll
        for (int i = 0; i < 8; ++i) g[i] = h2s[(size_t)(q[i].x & 0x1FFFF) * HID + lane];
#pragma unroll
        for (int i = 0; i < 8; ++i) accB += __half2float(g[i]);
    }
    for (; eB < mB; ++eB) {
        int2 q = epack[eB];
        accB += __half2float(h2s[(size_t)(q.x & 0x1FFFF) * HID + lane]);
    }
    float bv = b2[lane];
    {
        float dv = dis[vA];
        float self = __half2float(h2s[(size_t)vA * HID + lane]);   // = h2[vA]*dis[vA]
        float val = dv * (accA + self) + bv;
        val = val > 0.0f ? val : 0.0f;
        unsafeAtomicAdd(&pooled[batch[vA] * HID + lane], val);
    }
    {
        float dv = dis[vB];
        float self = __half2float(h2s[(size_t)vB * HID + lane]);
        float val = dv * (accB + self) + bv;
        val = val > 0.0f ? val : 0.0f;
        unsafeAtomicAdd(&pooled[batch[vB] * HID + lane], val);
    }
}

// ---------------- logits ----------------
__global__ __launch_bounds__(64) void logits_kernel(
    const float* __restrict__ pooled, const int* __restrict__ cnt,
    const float* __restrict__ Wl, const float* __restrict__ bl,
    float* __restrict__ out) {
    __shared__ float row[HID];
    int g = blockIdx.x, t = threadIdx.x;
    int c = cnt[g]; if (c < 1) c = 1;
    row[t] = pooled[g * HID + t] / (float)c;
    __syncthreads();
    if (t < N_CLASSES) {
        float acc = bl[t];
#pragma unroll
        for (int k = 0; k < HID; ++k) acc = fmaf(row[k], Wl[k * N_CLASSES + t], acc);
        out[g * N_CLASSES + t] = acc;
    }
}

extern "C" void kernel_launch(void* const* d_in, const int* in_sizes, int n_in,
                              void* d_out, int out_size, void* d_ws, size_t ws_size,
                              hipStream_t stream) {
    const int*   shape_id = (const int*)d_in[0];
    const int*   color_id = (const int*)d_in[1];
    const int*   edge_idx = (const int*)d_in[2];
    const int*   batch    = (const int*)d_in[3];
    const float* st       = (const float*)d_in[4];
    const float* ct       = (const float*)d_in[5];
    const float* W1       = (const float*)d_in[6];
    const float* b1       = (const float*)d_in[7];
    const float* W2       = (const float*)d_in[8];
    const float* b2       = (const float*)d_in[9];
    const float* Wl       = (const float*)d_in[10];
    const float* bl       = (const float*)d_in[11];
    float* out = (float*)d_out;

    const int* src = edge_idx;
    const int* dst = edge_idx + N_EDGES;

    // workspace layout — identical offsets to R10; x1 region now hosts gbin only.
    char* ws = (char*)d_ws;
    int*    combo  = (int*)   (ws + 0);            //   400,384 B
    float*  dis    = (float*) (ws + 400384);       //   400,384 B
    int*    degi   = (int*)   (ws + 800768);       //   400,384 B
    int*    rowptr = (int*)   (ws + 1201152);      //   400,384 B
    int*    bsum   = (int*)   (ws + 1601536);      //     2,048 B
    float*  TC     = (float*) (ws + 1603584);      //    39,424 B
    float*  pooled = (float*) (ws + 1643008);      //   262,144 B
    int*    cnt    = (int*)   (ws + 1905152);      //     4,096 B
    int*    gcur   = (int*)   (ws + 1909248);      //     1,024 B
    int2*   epack  = (int2*)  (ws + 1910272);      // 12,800,000 B
    int2*   gbin   = (int2*)  (ws + 14710272);     // 14,680,064 B
    __half* h2s    = (__half*)(ws + 40310272);     // 12,800,000 B (total ~53.1 MB)

    hipMemsetAsync(pooled, 0, N_GRAPHS * HID * sizeof(float) + N_GRAPHS * sizeof(int), stream);
    hipMemsetAsync(gcur, 0, NBUCK * sizeof(int), stream);

    // 1. per-node combo + per-graph counts
    prep_kernel<<<SCAN_BLOCKS, 256, 0, stream>>>(shape_id, color_id, batch, combo, cnt);

    // 2. combined (shape,color)->h1 table
    tc_kernel<<<NCOMBO, 64, 0, stream>>>(st, ct, W1, TC);

    // 3. bin edges by dst-bucket (chunked, coalesced writes)
    binA_kernel<<<(N_EDGES + EPB - 1) / EPB, 512, 0, stream>>>(src, dst, combo, gcur, gbin);

    // 4. per-bucket degree count + dis
    degB_kernel<<<NBUCK, 256, 0, stream>>>(gbin, gcur, degi, dis);

    // 5. exclusive scan -> rowptr
    scanA_kernel<<<SCAN_BLOCKS, 256, 0, stream>>>(degi, rowptr, bsum);
    scanB_kernel<<<1, 512, 0, stream>>>(bsum);
    scanC_kernel<<<SCAN_BLOCKS, 256, 0, stream>>>(rowptr, bsum);

    // 6. per-bucket scatter to CSR (single-XCD windows)
    binB_kernel<<<NBUCK, 256, 0, stream>>>(gbin, gcur, rowptr, dis, epack);

    // 7. fused layer-1 aggregate + mm2 -> h2s (fp16, prescaled by dis)
    agg1_mm2_kernel<<<6250, 256, 0, stream>>>(epack, rowptr, combo, dis, TC, W2, b1, h2s);

    // 8. layer-2 aggregate + pool (paired nodes, prescaled h2s)
    agg2_pool_kernel<<<N_NODES / 8, 256, 0, stream>>>(epack, rowptr, h2s, dis, b2,
                                                      batch, pooled);

    // 9. logits
    logits_kernel<<<N_GRAPHS, 64, 0, stream>>>(pooled, cnt, Wl, bl, out);
}

// Round 12
// 294.250 us; speedup vs baseline: 1.3353x; 1.0557x over previous
//
#include <hip/hip_runtime.h>
#include <hip/hip_bf16.h>
#include <hip/hip_fp16.h>

#define N_NODES   100000
#define N_EDGES   1600000
#define N_GRAPHS  1024
#define EMB       32
#define HID       64
#define N_CLASSES 10
#define SCAN_BLOCKS 391   // ceil(100000/256)
#define NCOMBO 153        // 17 shape ids x 9 color ids
#define BUCK_NODES 448    // nodes per dst-bucket
#define NBUCK 224         // ceil(100000/448)
#define BIN_CAP 8192      // per-bucket staging capacity (mean 7143, +12 sigma)
#define EPB 8192          // edges per binA block

// ---------------- prep: combo[v], per-graph counts ----------------
__global__ __launch_bounds__(256) void prep_kernel(
    const int* __restrict__ sid, const int* __restrict__ cid,
    const int* __restrict__ batch, int* __restrict__ combo, int* __restrict__ cnt) {
    int v = blockIdx.x * 256 + threadIdx.x;
    if (v < N_NODES) {
        combo[v] = sid[v] * 9 + cid[v];
        atomicAdd(&cnt[batch[v]], 1);
    }
}

// ---------------- combined table (fp16): TCh[s*9+c][j] = (st[s]@W1)[j] + (ct[c]@W1)[j] ----------------
__global__ __launch_bounds__(64) void tc_kernel(
    const float* __restrict__ st, const float* __restrict__ ct,
    const float* __restrict__ W1, __half* __restrict__ TCh) {
    int r = blockIdx.x, j = threadIdx.x;
    int s = r / 9, c = r % 9;
    float acc = 0.0f;
    if (s != 0) {
#pragma unroll
        for (int k = 0; k < EMB; ++k) acc = fmaf(st[s * EMB + k], W1[k * HID + j], acc);
    }
    if (c != 0) {
#pragma unroll
        for (int k = 0; k < EMB; ++k) acc = fmaf(ct[c * EMB + k], W1[k * HID + j], acc);
    }
    TCh[r * HID + j] = __float2half_rn(acc);
}

// ---------------- binA: block-local counting sort by dst-bucket, chunked flush ----------------
__global__ __launch_bounds__(512) void binA_kernel(
    const int* __restrict__ src, const int* __restrict__ dst,
    const int* __restrict__ combo, int* __restrict__ gcur,
    int2* __restrict__ gbin) {
    __shared__ int2 stg[EPB];            // 64 KB
    __shared__ int hist[NBUCK];
    __shared__ int base[NBUCK + 1];
    __shared__ int gstart[NBUCK];
    __shared__ int scanbuf[256];
    int t = threadIdx.x;
    int e0 = blockIdx.x * EPB;
    for (int i = t; i < NBUCK; i += 512) hist[i] = 0;
    __syncthreads();

    int2 myq[16];
    int mybo[16];
#pragma unroll
    for (int i = 0; i < 16; ++i) {
        int e = e0 + t + i * 512;
        if (e < N_EDGES) {
            int d = dst[e];
            int s = src[e];
            unsigned b = (unsigned)d / BUCK_NODES;
            int off = atomicAdd(&hist[b], 1);
            myq[i].x = s | (combo[s] << 17);
            myq[i].y = d;
            mybo[i] = (int)(b << 16) | off;
        } else {
            mybo[i] = -1;
        }
    }
    __syncthreads();

    int h = (t < NBUCK) ? hist[t] : 0;
    if (t < 256) scanbuf[t] = h;
    __syncthreads();
#pragma unroll
    for (int off = 1; off < 256; off <<= 1) {
        int x = (t < 256 && t >= off) ? scanbuf[t - off] : 0;
        __syncthreads();
        if (t < 256) scanbuf[t] += x;
        __syncthreads();
    }
    if (t < NBUCK) base[t] = scanbuf[t] - h;
    if (t == 0) base[NBUCK] = scanbuf[255];
    __syncthreads();
#pragma unroll
    for (int i = 0; i < 16; ++i) {
        if (mybo[i] >= 0) {
            int b = mybo[i] >> 16, off = mybo[i] & 0xFFFF;
            stg[base[b] + off] = myq[i];
        }
    }
    if (t < NBUCK) {
        int n = hist[t];
        gstart[t] = n ? atomicAdd(&gcur[t], n) : 0;
    }
    __syncthreads();
    int total = base[NBUCK];
    for (int i = t; i < total; i += 512) {
        int2 q = stg[i];
        unsigned b = (unsigned)q.y / BUCK_NODES;
        gbin[(size_t)b * BIN_CAP + gstart[b] + (i - base[b])] = q;
    }
}

// ---------------- degB: per-bucket degree count; dis = rsqrt(1+deg) ----------------
__global__ __launch_bounds__(256) void degB_kernel(
    const int2* __restrict__ gbin, const int* __restrict__ gcur,
    int* __restrict__ degi, float* __restrict__ dis) {
    __shared__ int curs[BUCK_NODES];
    int b = blockIdx.x, t = threadIdx.x;
    for (int i = t; i < BUCK_NODES; i += 256) curs[i] = 0;
    __syncthreads();
    int n = gcur[b];
    const int2* mybin = gbin + (size_t)b * BIN_CAP;
    for (int i = t; i < n; i += 256) {
        int2 q = mybin[i];
        atomicAdd(&curs[q.y - b * BUCK_NODES], 1);
    }
    __syncthreads();
    for (int i = t; i < BUCK_NODES; i += 256) {
        int v = b * BUCK_NODES + i;
        if (v < N_NODES) {
            int d = curs[i];
            degi[v] = d;
            dis[v] = rsqrtf(1.0f + (float)d);
        }
    }
}

// ---------------- 3-pass exclusive scan of degrees -> rowptr ----------------
__global__ __launch_bounds__(256) void scanA_kernel(const int* __restrict__ degi,
                                                    int* __restrict__ rowptr,
                                                    int* __restrict__ bsum) {
    __shared__ int s[256];
    int t = threadIdx.x, b = blockIdx.x;
    int v = b * 256 + t;
    int d = (v < N_NODES) ? degi[v] : 0;
    s[t] = d; __syncthreads();
#pragma unroll
    for (int off = 1; off < 256; off <<= 1) {
        int x = (t >= off) ? s[t - off] : 0;
        __syncthreads();
        s[t] += x;
        __syncthreads();
    }
    if (v < N_NODES) rowptr[v] = s[t] - d;
    if (t == 255) bsum[b] = s[255];
}

__global__ __launch_bounds__(512) void scanB_kernel(int* __restrict__ bsum) {
    __shared__ int s[512];
    int t = threadIdx.x;
    int d = (t < SCAN_BLOCKS) ? bsum[t] : 0;
    s[t] = d; __syncthreads();
#pragma unroll
    for (int off = 1; off < 512; off <<= 1) {
        int x = (t >= off) ? s[t - off] : 0;
        __syncthreads();
        s[t] += x;
        __syncthreads();
    }
    if (t < SCAN_BLOCKS) bsum[t] = s[t] - d;
}

__global__ __launch_bounds__(256) void scanC_kernel(int* __restrict__ rowptr,
                                                    const int* __restrict__ bsum) {
    int t = threadIdx.x, b = blockIdx.x;
    int v = b * 256 + t;
    if (v < N_NODES) rowptr[v] += bsum[b];
    if (b == 0 && t == 0) rowptr[N_NODES] = N_EDGES;
}

// ---------------- binB: per-bucket fine scatter to CSR ----------------
__global__ __launch_bounds__(256) void binB_kernel(
    const int2* __restrict__ gbin, const int* __restrict__ gcur,
    const int* __restrict__ rowptr, const float* __restrict__ dis,
    int2* __restrict__ epack) {
    __shared__ int curs[BUCK_NODES];
    int b = blockIdx.x, t = threadIdx.x;
    for (int i = t; i < BUCK_NODES; i += 256) curs[i] = 0;
    __syncthreads();
    int n = gcur[b];
    const int2* mybin = gbin + (size_t)b * BIN_CAP;
    for (int i = t; i < n; i += 256) {
        int2 q = mybin[i];
        int local = q.y - b * BUCK_NODES;
        int r = atomicAdd(&curs[local], 1);
        int2 rec;
        rec.x = q.x;
        rec.y = __float_as_int(dis[q.x & 0x1FFFF]);
        epack[rowptr[q.y] + r] = rec;
    }
}

// ---------------- fused layer-1 aggregate + mm2: h2s = (x1 @ W2) * dis[v], fp16 ----------------
// fp16 TC table: LDS = 19.6 KB + 1 KB -> ~7 blocks/CU (vs 3 at fp32 table).
__global__ __launch_bounds__(256) void agg1_mm2_kernel(
    const int2* __restrict__ epack, const int* __restrict__ rowptr,
    const int* __restrict__ combo, const float* __restrict__ dis,
    const __half* __restrict__ TCh, const float* __restrict__ W2,
    const float* __restrict__ b1, __half* __restrict__ h2s) {
    __shared__ __align__(16) __half TCs[NCOMBO * HID];  // 19,584 B
    __shared__ __align__(16) float xs[4][HID];          //  1,024 B
    int t = threadIdx.x;
    {
        const int4* s4 = (const int4*)TCh;
        int4* d4 = (int4*)TCs;
        for (int i = t; i < NCOMBO * HID * 2 / 16; i += 256) d4[i] = s4[i];
    }
    __syncthreads();
    int lane = t & 63, w = t >> 6;
    float bias = b1[lane];
    float wcol[HID];
#pragma unroll
    for (int k = 0; k < HID; ++k) wcol[k] = W2[k * HID + lane];
    int v0 = (blockIdx.x * 4 + w) * 4;
    for (int n = 0; n < 4; ++n) {
        int v = v0 + n;
        int e  = __builtin_amdgcn_readfirstlane(rowptr[v]);
        int e1 = __builtin_amdgcn_readfirstlane(rowptr[v + 1]);
        float acc = 0.0f;
        for (; e + 8 <= e1; e += 8) {
            int2 q[8];
#pragma unroll
            for (int i = 0; i < 8; ++i) q[i] = epack[e + i];
            __half tv[8];
#pragma unroll
            for (int i = 0; i < 8; ++i)
                tv[i] = TCs[((unsigned)q[i].x >> 17) * HID + lane];
#pragma unroll
            for (int i = 0; i < 8; ++i)
                acc = fmaf(__int_as_float(q[i].y), __half2float(tv[i]), acc);
        }
        for (; e < e1; ++e) {
            int2 q = epack[e];
            acc = fmaf(__int_as_float(q.y),
                       __half2float(TCs[((unsigned)q.x >> 17) * HID + lane]), acc);
        }
        float dv = dis[v];
        float hv = __half2float(TCs[combo[v] * HID + lane]);
        float val = dv * fmaf(hv, dv, acc) + bias;
        val = val > 0.0f ? val : 0.0f;              // x1[v][lane]

        // h2s[v][lane] = (sum_k x1[v][k] * W2[k][lane]) * dis[v]
        xs[w][lane] = val;                          // wave-coherent staging
        float acc2 = 0.0f;
#pragma unroll
        for (int k4 = 0; k4 < HID / 4; ++k4) {
            float4 xv = *(const float4*)(&xs[w][k4 * 4]);   // broadcast read
            acc2 = fmaf(xv.x, wcol[k4 * 4 + 0], acc2);
            acc2 = fmaf(xv.y, wcol[k4 * 4 + 1], acc2);
            acc2 = fmaf(xv.z, wcol[k4 * 4 + 2], acc2);
            acc2 = fmaf(xv.w, wcol[k4 * 4 + 3], acc2);
        }
        h2s[(size_t)v * HID + lane] = __float2half_rn(acc2 * dv);
    }
}

// ---------------- layer-2 aggregate + pool: paired nodes, prescaled h2s ----------------
__global__ __launch_bounds__(256) void agg2_pool_kernel(
    const int2* __restrict__ epack, const int* __restrict__ rowptr,
    const __half* __restrict__ h2s, const float* __restrict__ dis,
    const float* __restrict__ b2, const int* __restrict__ batch,
    float* __restrict__ pooled) {
    int t = threadIdx.x, lane = t & 63, w = t >> 6;
    int vA = (blockIdx.x * 4 + w) * 2;      // grid 12500: vA,vB always < N_NODES
    int vB = vA + 1;
    int eA = __builtin_amdgcn_readfirstlane(rowptr[vA]);
    int mA = __builtin_amdgcn_readfirstlane(rowptr[vA + 1]);
    int eB = mA;
    int mB = __builtin_amdgcn_readfirstlane(rowptr[vB + 1]);
    float accA = 0.0f, accB = 0.0f;
    while (eA + 8 <= mA && eB + 8 <= mB) {
        int2 qA[8], qB[8];
#pragma unroll
        for (int i = 0; i < 8; ++i) { qA[i] = epack[eA + i]; qB[i] = epack[eB + i]; }
        __half gA[8], gB[8];
#pragma unroll
        for (int i = 0; i < 8; ++i) {
            gA[i] = h2s[(size_t)(qA[i].x & 0x1FFFF) * HID + lane];
            gB[i] = h2s[(size_t)(qB[i].x & 0x1FFFF) * HID + lane];
        }
#pragma unroll
        for (int i = 0; i < 8; ++i) {
            accA += __half2float(gA[i]);
            accB += __half2float(gB[i]);
        }
        eA += 8; eB += 8;
    }
    for (; eA + 8 <= mA; eA += 8) {
        int2 q[8];
#pragma unroll
        for (int i = 0; i < 8; ++i) q[i] = epack[eA + i];
        __half g[8];
#pragma unroll
        for (int i = 0; i < 8; ++i) g[i] = h2s[(size_t)(q[i].x & 0x1FFFF) * HID + lane];
#pragma unroll
        for (int i = 0; i < 8; ++i) accA += __half2float(g[i]);
    }
    for (; eA < mA; ++eA) {
        int2 q = epack[eA];
        accA += __half2float(h2s[(size_t)(q.x & 0x1FFFF) * HID + lane]);
    }
    for (; eB + 8 <= mB; eB += 8) {
        int2 q[8];
#pragma unroll
        for (int i = 0; i < 8; ++i) q[i] = epack[eB + i];
        __half g[8];
#pragma unroll
        for (int i = 0; i < 8; ++i) g[i] = h2s[(size_t)(q[i].x & 0x1FFFF) * HID + lane];
#pragma unroll
        for (int i = 0; i < 8; ++i) accB += __half2float(g[i]);
    }
    for (; eB < mB; ++eB) {
        int2 q = epack[eB];
        accB += __half2float(h2s[(size_t)(q.x & 0x1FFFF) * HID + lane]);
    }
    float bv = b2[lane];
    {
        float dv = dis[vA];
        float self = __half2float(h2s[(size_t)vA * HID + lane]);
        float val = dv * (accA + self) + bv;
        val = val > 0.0f ? val : 0.0f;
        unsafeAtomicAdd(&pooled[batch[vA] * HID + lane], val);
    }
    {
        float dv = dis[vB];
        float self = __half2float(h2s[(size_t)vB * HID + lane]);
        float val = dv * (accB + self) + bv;
        val = val > 0.0f ? val : 0.0f;
        unsafeAtomicAdd(&pooled[batch[vB] * HID + lane], val);
    }
}

// ---------------- logits ----------------
__global__ __launch_bounds__(64) void logits_kernel(
    const float* __restrict__ pooled, const int* __restrict__ cnt,
    const float* __restrict__ Wl, const float* __restrict__ bl,
    float* __restrict__ out) {
    __shared__ float row[HID];
    int g = blockIdx.x, t = threadIdx.x;
    int c = cnt[g]; if (c < 1) c = 1;
    row[t] = pooled[g * HID + t] / (float)c;
    __syncthreads();
    if (t < N_CLASSES) {
        float acc = bl[t];
#pragma unroll
        for (int k = 0; k < HID; ++k) acc = fmaf(row[k], Wl[k * N_CLASSES + t], acc);
        out[g * N_CLASSES + t] = acc;
    }
}

extern "C" void kernel_launch(void* const* d_in, const int* in_sizes, int n_in,
                              void* d_out, int out_size, void* d_ws, size_t ws_size,
                              hipStream_t stream) {
    const int*   shape_id = (const int*)d_in[0];
    const int*   color_id = (const int*)d_in[1];
    const int*   edge_idx = (const int*)d_in[2];
    const int*   batch    = (const int*)d_in[3];
    const float* st       = (const float*)d_in[4];
    const float* ct       = (const float*)d_in[5];
    const float* W1       = (const float*)d_in[6];
    const float* b1       = (const float*)d_in[7];
    const float* W2       = (const float*)d_in[8];
    const float* b2       = (const float*)d_in[9];
    const float* Wl       = (const float*)d_in[10];
    const float* bl       = (const float*)d_in[11];
    float* out = (float*)d_out;

    const int* src = edge_idx;
    const int* dst = edge_idx + N_EDGES;

    // workspace layout
    char* ws = (char*)d_ws;
    int*    combo  = (int*)   (ws + 0);            //   400,384 B
    float*  dis    = (float*) (ws + 400384);       //   400,384 B
    int*    degi   = (int*)   (ws + 800768);       //   400,384 B
    int*    rowptr = (int*)   (ws + 1201152);      //   400,384 B
    int*    bsum   = (int*)   (ws + 1601536);      //     2,048 B
    __half* TCh    = (__half*)(ws + 1603584);      //    19,968 B
    float*  pooled = (float*) (ws + 1623552);      //   262,144 B
    int*    cnt    = (int*)   (ws + 1885696);      //     4,096 B
    int*    gcur   = (int*)   (ws + 1889792);      //     1,024 B
    int2*   epack  = (int2*)  (ws + 1890816);      // 12,800,000 B
    int2*   gbin   = (int2*)  (ws + 14690816);     // 14,680,064 B
    __half* h2s    = (__half*)(ws + 29370880);     // 12,800,000 B (total ~42.2 MB)

    hipMemsetAsync(pooled, 0, N_GRAPHS * HID * sizeof(float) + N_GRAPHS * sizeof(int), stream);
    hipMemsetAsync(gcur, 0, NBUCK * sizeof(int), stream);

    // 1. per-node combo + per-graph counts
    prep_kernel<<<SCAN_BLOCKS, 256, 0, stream>>>(shape_id, color_id, batch, combo, cnt);

    // 2. combined (shape,color)->h1 table (fp16)
    tc_kernel<<<NCOMBO, 64, 0, stream>>>(st, ct, W1, TCh);

    // 3. bin edges by dst-bucket (chunked, coalesced writes)
    binA_kernel<<<(N_EDGES + EPB - 1) / EPB, 512, 0, stream>>>(src, dst, combo, gcur, gbin);

    // 4. per-bucket degree count + dis
    degB_kernel<<<NBUCK, 256, 0, stream>>>(gbin, gcur, degi, dis);

    // 5. exclusive scan -> rowptr
    scanA_kernel<<<SCAN_BLOCKS, 256, 0, stream>>>(degi, rowptr, bsum);
    scanB_kernel<<<1, 512, 0, stream>>>(bsum);
    scanC_kernel<<<SCAN_BLOCKS, 256, 0, stream>>>(rowptr, bsum);

    // 6. per-bucket scatter to CSR (single-XCD windows)
    binB_kernel<<<NBUCK, 256, 0, stream>>>(gbin, gcur, rowptr, dis, epack);

    // 7. fused layer-1 aggregate + mm2 -> h2s (fp16 table, fp16 out, prescaled)
    agg1_mm2_kernel<<<6250, 256, 0, stream>>>(epack, rowptr, combo, dis, TCh, W2, b1, h2s);

    // 8. layer-2 aggregate + pool (paired nodes, prescaled h2s)
    agg2_pool_kernel<<<N_NODES / 8, 256, 0, stream>>>(epack, rowptr, h2s, dis, b2,
                                                      batch, pooled);

    // 9. logits
    logits_kernel<<<N_GRAPHS, 64, 0, stream>>>(pooled, cnt, Wl, bl, out);
}